// Round 1
// baseline (19.623 us; speedup 1.0000x reference)
//
#include <hip/hip_runtime.h>
#include <math.h>

// Problem constants (hardcoded in reference)
#define B_  15
#define TO_ 10   // T_OUT
#define TI_ 10   // T_IN
#define H_  4
#define G_  16   // 4*H
#define D_  512

// ---------------------------------------------------------------------------
// Kernel 1: xg[b*T+t][g] = sum_d x[b,t,d] * W_ih[g,d] + b_ih[g] + b_hh[g]
// One 64-lane wave per (row, gate) dot product. 150 rows * 16 gates = 2400
// waves. Coalesced stride-64 loads, full-wave shuffle reduction.
// ---------------------------------------------------------------------------
__global__ void xg_proj_kernel(const float* __restrict__ x,
                               const float* __restrict__ W,
                               const float* __restrict__ b_ih,
                               const float* __restrict__ b_hh,
                               float* __restrict__ xg) {
    int gwave = (blockIdx.x * blockDim.x + threadIdx.x) >> 6;
    int lane  = threadIdx.x & 63;
    if (gwave >= B_ * TO_ * G_) return;
    int row = gwave >> 4;      // b*TO_ + t
    int g   = gwave & 15;
    const float* xr = x + (size_t)row * D_;
    const float* wr = W + (size_t)g   * D_;
    float sum = 0.f;
#pragma unroll
    for (int d = lane; d < D_; d += 64) sum += xr[d] * wr[d];
#pragma unroll
    for (int off = 32; off; off >>= 1) sum += __shfl_down(sum, off);
    if (lane == 0) xg[row * G_ + g] = sum + b_ih[g] + b_hh[g];
}

__device__ __forceinline__ float sigf(float x) { return 1.0f / (1.0f + expf(-x)); }

// ---------------------------------------------------------------------------
// Kernel 2: single block, whole serial tail (LSTM scan + buggy attention).
// ---------------------------------------------------------------------------
__global__ void __launch_bounds__(256) lstm_attn_kernel(
        const float* __restrict__ xg,   // [B*TO, 16]
        const float* __restrict__ h0,   // [1,B,H] -> flat 60
        const float* __restrict__ c0,   // flat 60
        const float* __restrict__ enc,  // [B,TI,H] flat 600
        const float* __restrict__ Whh,  // [16,4]
        float* __restrict__ out) {      // [B,TO,8] flat 1200
    __shared__ float sW[G_][H_];
    __shared__ float h_s[B_][H_];
    __shared__ float c_s[B_][H_];
    __shared__ float gates[B_][G_];
    __shared__ float att[B_][TO_][H_];
    __shared__ float enc_s[B_][TI_][H_];
    __shared__ float ex[B_][TO_][TI_];
    __shared__ float ssum[B_][TO_];

    int tid = threadIdx.x;

    if (tid < G_ * H_) ((float*)sW)[tid] = Whh[tid];
    if (tid < B_ * H_) {
        ((float*)h_s)[tid] = h0[tid];
        ((float*)c_s)[tid] = c0[tid];
    }
    for (int i = tid; i < B_ * TI_ * H_; i += blockDim.x)
        ((float*)enc_s)[i] = enc[i];
    __syncthreads();

    // ---- LSTM scan over t ----
    for (int t = 0; t < TO_; ++t) {
        if (tid < B_ * G_) {
            int b = tid >> 4, g = tid & 15;
            float v = xg[(b * TO_ + t) * G_ + g];
#pragma unroll
            for (int j = 0; j < H_; ++j) v += h_s[b][j] * sW[g][j];
            gates[b][g] = v;
        }
        __syncthreads();
        if (tid < B_ * H_) {
            int b = tid >> 2, j = tid & 3;
            float ig = gates[b][j];
            float fg = gates[b][4 + j];
            float gg = gates[b][8 + j];
            float og = gates[b][12 + j];
            float c  = sigf(fg) * c_s[b][j] + sigf(ig) * tanhf(gg);
            float h  = sigf(og) * tanhf(c);
            c_s[b][j] = c;
            h_s[b][j] = h;
            att[b][t][j] = h;
        }
        __syncthreads();
    }

    // ---- ex[b][l][k] = exp(<att[b][l], enc[b][k]>) ----
    for (int i = tid; i < B_ * TO_ * TI_; i += blockDim.x) {
        int b = i / (TO_ * TI_);
        int r = i % (TO_ * TI_);
        int l = r / TI_, k = r % TI_;
        float d = 0.f;
#pragma unroll
        for (int j = 0; j < H_; ++j) d += att[b][l][j] * enc_s[b][k][j];
        ex[b][l][k] = expf(d);
    }
    __syncthreads();

    // ---- row sums ----
    if (tid < B_ * TO_) {
        int b = tid / TO_, l = tid % TO_;
        float s = 0.f;
#pragma unroll
        for (int k = 0; k < TI_; ++k) s += ex[b][l][k];
        ssum[b][l] = s;
    }
    __syncthreads();

    // ---- faithful bug: only LAST key column divided by s^T_IN ----
    if (tid < B_ * TO_) {
        int b = tid / TO_, l = tid % TO_;
        double s = (double)ssum[b][l];
        double p = 1.0;
#pragma unroll
        for (int q = 0; q < TI_; ++q) p *= s;   // s^10 in double (no fp32 overflow)
        ex[b][l][TI_ - 1] = (float)((double)ex[b][l][TI_ - 1] / p);
    }
    __syncthreads();

    // ---- cumprod over l (axis=1), in place, per (b,k) column ----
    if (tid < B_ * TI_) {
        int b = tid / TI_, k = tid % TI_;
        float prod = 1.f;
#pragma unroll
        for (int l = 0; l < TO_; ++l) {
            prod *= ex[b][l][k];
            ex[b][l][k] = prod;
        }
    }
    __syncthreads();

    // ---- cn[b][l][d] = sum_k cumw * enc ; out = concat([cn, att], -1) ----
    for (int i = tid; i < B_ * TO_ * H_; i += blockDim.x) {
        int b = i / (TO_ * H_);
        int r = i % (TO_ * H_);
        int l = r / H_, d = r % H_;
        float cn = 0.f;
#pragma unroll
        for (int k = 0; k < TI_; ++k) cn += ex[b][l][k] * enc_s[b][k][d];
        float* o = out + ((size_t)(b * TO_ + l)) * (2 * H_);
        o[d]       = cn;
        o[H_ + d]  = att[b][l][d];
    }
}

extern "C" void kernel_launch(void* const* d_in, const int* in_sizes, int n_in,
                              void* d_out, int out_size, void* d_ws, size_t ws_size,
                              hipStream_t stream) {
    const float* x     = (const float*)d_in[0];  // [15,10,512]
    const float* h0    = (const float*)d_in[1];  // [1,15,4]
    const float* c0    = (const float*)d_in[2];  // [1,15,4]
    const float* enc   = (const float*)d_in[3];  // [15,10,4]
    const float* W_ih  = (const float*)d_in[4];  // [16,512]
    const float* W_hh  = (const float*)d_in[5];  // [16,4]
    const float* b_ih  = (const float*)d_in[6];  // [16]
    const float* b_hh  = (const float*)d_in[7];  // [16]
    float*       out   = (float*)d_out;          // [15,10,8]
    float*       xg    = (float*)d_ws;           // 2400 floats scratch

    // 2400 waves, 4 waves per 256-thread block -> 600 blocks
    xg_proj_kernel<<<600, 256, 0, stream>>>(x, W_ih, b_ih, b_hh, xg);
    lstm_attn_kernel<<<1, 256, 0, stream>>>(xg, h0, c0, enc, W_hh, out);
}